// Round 10
// baseline (243.170 us; speedup 1.0000x reference)
//
#include <hip/hip_runtime.h>
#include <cstdint>
#include <cstddef>

typedef unsigned short u16;
typedef __attribute__((ext_vector_type(8))) short short8;
typedef __attribute__((ext_vector_type(4))) float v4f;

static constexpr size_t NN = (size_t)2048 * 2048;
#define N2 2048

typedef __attribute__((address_space(1))) const unsigned int guint;
typedef __attribute__((address_space(3))) unsigned int luint;

__device__ __forceinline__ float b2f_bits(uint32_t hi) { union { uint32_t u; float f; } v; v.u = hi; return v.f; }
__device__ __forceinline__ float b2f(u16 x) { return b2f_bits((uint32_t)x << 16); }
__device__ __forceinline__ u16 f2b(float f) {
  union { float f; uint32_t u; } v; v.f = f;
  uint32_t r = v.u + 0x7fffu + ((v.u >> 16) & 1u);
  return (u16)(r >> 16);
}
// HW packed f32->bf16 (RNE), 2 values/instr.
__device__ __forceinline__ uint32_t cvt2(float lo, float hi) {
  uint32_t r;
  asm("v_cvt_pk_bf16_f32 %0, %1, %2" : "=v"(r) : "v"(lo), "v"(hi));
  return r;
}
__device__ __forceinline__ uint4 pack8(const float* f) {
  uint4 u;
  u.x = cvt2(f[0], f[1]);
  u.y = cvt2(f[2], f[3]);
  u.z = cvt2(f[4], f[5]);
  u.w = cvt2(f[6], f[7]);
  return u;
}
// wave-uniform value -> SGPR
__device__ __forceinline__ float sgprf(float x) {
  union { float f; int i; } v; v.f = x;
  v.i = __builtin_amdgcn_readfirstlane(v.i);
  return v.f;
}

// ---------------------------------------------------------------------------
// K0: one pass over fp32 A[5][N][N], 64x64 tiles, 512 threads. abf, a1r
// row-major; bbt, a1t transposed via XOR-swizzled two-phase LDS (16 KB).
// Xw^T fold: ALL 1024 blocks, 2 rows each, 4 threads/elem (64-iter partial +
// 2-lane butterfly) -- kills the R8 straggler tail.
// ---------------------------------------------------------------------------
__global__ __launch_bounds__(512, 2) void conv_kernel(
    const float* __restrict__ A, const float* __restrict__ w1,
    const float* __restrict__ w2, const float* __restrict__ w3,
    const float* __restrict__ X, const float* __restrict__ W,
    u16* __restrict__ abf, u16* __restrict__ bbt, u16* __restrict__ a1t,
    u16* __restrict__ a1r, u16* __restrict__ Xwt)
{
  __shared__ u16 LT[2][64 * 64];   // [b_c, a1_c], transposed+swizzled
  const int t = threadIdx.x;
  const int bid = (int)(blockIdx.y * 32 + blockIdx.x);
  const int i0 = blockIdx.y * 64, j0 = blockIdx.x * 64;
  const int m = t >> 3;            // tile row 0..63
  const int cg = t & 7;            // colgroup 0..7
  const int n0 = cg * 8;           // col base

  // softmax weights -> SGPRs
  float sc[3][2][5];
  {
    const float* wsrc[3] = { w1, w2, w3 };
    for (int q = 0; q < 3; ++q)
      for (int c = 0; c < 2; ++c) {
        float v[5], mx = -1e30f, sum = 0.f;
        #pragma unroll
        for (int e = 0; e < 5; ++e) { v[e] = wsrc[q][c * 5 + e]; mx = fmaxf(mx, v[e]); }
        #pragma unroll
        for (int e = 0; e < 5; ++e) { v[e] = expf(v[e] - mx); sum += v[e]; }
        #pragma unroll
        for (int e = 0; e < 5; ++e) sc[q][c][e] = sgprf(v[e] / sum);
      }
  }

  float av[2][8], bv[2][8], cv[2][8];
  #pragma unroll
  for (int c = 0; c < 2; ++c)
    #pragma unroll
    for (int u = 0; u < 8; ++u) { av[c][u] = 0.f; bv[c][u] = 0.f; cv[c][u] = 0.f; }

  #pragma unroll
  for (int e = 0; e < 5; ++e) {
    const float* base = A + (size_t)e * NN + (size_t)(i0 + m) * N2 + (j0 + n0);
    float4 x0 = ((const float4*)base)[0];
    float4 x1 = ((const float4*)base)[1];
    float f[8] = { x0.x, x0.y, x0.z, x0.w, x1.x, x1.y, x1.z, x1.w };
    #pragma unroll
    for (int c = 0; c < 2; ++c)
      #pragma unroll
      for (int u = 0; u < 8; ++u) {
        av[c][u] += sc[0][c][e] * f[u];
        bv[c][u] += sc[1][c][e] * f[u];
        cv[c][u] += sc[2][c][e] * f[u];
      }
  }

  // row-major outputs: 16B/lane, 8 lanes cover a 128B line
  #pragma unroll
  for (int c = 0; c < 2; ++c) {
    *(uint4*)(abf + (size_t)c * NN + (size_t)(i0 + m) * N2 + (j0 + n0)) = pack8(av[c]);
    *(uint4*)(a1r + (size_t)c * NN + (size_t)(i0 + m) * N2 + (j0 + n0)) = pack8(cv[c]);
  }
  // two-phase transposed stash (swizzled scalar stores, 2-way banks = free);
  // pairs converted via cvt_pk, halves split to rows u and u+1 (idx+64).
  const int swb = ((m >> 3) ^ cg) & 7;
  const int mlo = m & 7;
  const int on = t >> 3;          // output row (tile col n)
  const int mb = t & 7;           // m-block
  const int src = on * 64 + (((mb ^ (on >> 3)) & 7) * 8);
  #pragma unroll
  for (int c = 0; c < 2; ++c) {
    if (c == 1) __syncthreads();
    #pragma unroll
    for (int u = 0; u < 8; u += 2) {
      const int idx = (n0 + u) * 64 + swb * 8 + mlo;
      const uint32_t pb = cvt2(bv[c][u], bv[c][u + 1]);
      const uint32_t pc = cvt2(cv[c][u], cv[c][u + 1]);
      LT[0][idx]      = (u16)pb;
      LT[0][idx + 64] = (u16)(pb >> 16);
      LT[1][idx]      = (u16)pc;
      LT[1][idx + 64] = (u16)(pc >> 16);
    }
    __syncthreads();
    *(uint4*)(bbt + (size_t)c * NN + (size_t)(j0 + on) * N2 + (i0 + mb * 8)) =
        *(const uint4*)&LT[0][src];
    *(uint4*)(a1t + (size_t)c * NN + (size_t)(j0 + on) * N2 + (i0 + mb * 8)) =
        *(const uint4*)&LT[1][src];
  }
  // Folded Xw^T: all blocks, 2 rows each, 4 threads/elem (64 iters + butterfly).
  {
    const int elem = t >> 2, q = t & 3;    // elem 0..127, K-quarter
    const int n = bid * 2 + (elem >> 6);
    const int k = elem & 63;
    const float* xr = X + n * 256 + q * 64;
    const float* wr = W + (size_t)(q * 64) * 64 + k;
    float acc = 0.f;
    #pragma unroll 8
    for (int mm = 0; mm < 64; ++mm)
      acc += xr[mm] * wr[mm * 64];
    acc += __shfl_xor(acc, 1);
    acc += __shfl_xor(acc, 2);
    if (q == 0) Xwt[(size_t)k * N2 + n] = f2b(acc);
  }
}

// ---------------------------------------------------------------------------
// bf16 MFMA GEMM (glds staging, 128x128 tile, BK=64, 256 thr), called with
// A=bbt (b^T row-major), Bt=abf (a row-major): C' = b^T @ a^T = Ht DIRECTLY
// (row-major) -- no transpose epilogue needed. Emits:
//   csp[c][bx][2048] = ROW sums of Ht (= column sums of H) via shfl-reduce,
//   diag[c][2048]    = diagonal (transpose-invariant),
//   Cout             = bf16 Ht row-major via two-phase coalescing LDS store.
// ---------------------------------------------------------------------------
__global__ __launch_bounds__(256, 3) void gemm_kernel(
    const u16* __restrict__ Ain, const u16* __restrict__ Btin,
    u16* __restrict__ Cout, float* __restrict__ csp, float* __restrict__ diag)
{
  const int c = blockIdx.z;
  const u16* Ac = Ain + (size_t)c * NN;
  const u16* Bc = Btin + (size_t)c * NN;
  const int m0 = blockIdx.y * 128, n0 = blockIdx.x * 128;
  const int t = threadIdx.x, w = t >> 6, lane = t & 63;
  const int quad = lane >> 4, r = lane & 15;
  __shared__ u16 SM[128 * 64 + 128 * 64];   // As | Bs (32 KB)
  u16* As = SM;
  u16* Bs = SM + 128 * 64;

  v4f zero4 = { 0.f, 0.f, 0.f, 0.f };
  v4f acc[2][8];
  #pragma unroll
  for (int i = 0; i < 2; ++i)
    #pragma unroll
    for (int j = 0; j < 8; ++j) acc[i][j] = zero4;

  const int srow = lane >> 3;            // row within an 8-row chunk
  const int sgran = (lane & 7) ^ srow;   // swizzled k-granule

  for (int kt = 0; kt < 2048; kt += 64) {
    __syncthreads();
    #pragma unroll
    for (int i = 0; i < 4; ++i) {
      const int chunk = i * 4 + w;
      const u16* ga = Ac + (size_t)(m0 + chunk * 8 + srow) * N2 + kt + sgran * 8;
      __builtin_amdgcn_global_load_lds((guint*)ga, (luint*)(As + chunk * 512), 16, 0, 0);
    }
    #pragma unroll
    for (int i = 0; i < 4; ++i) {
      const int chunk = i * 4 + w;
      const u16* gb = Bc + (size_t)(n0 + chunk * 8 + srow) * N2 + kt + sgran * 8;
      __builtin_amdgcn_global_load_lds((guint*)gb, (luint*)(Bs + chunk * 512), 16, 0, 0);
    }
    __syncthreads();
    #pragma unroll
    for (int ks = 0; ks < 2; ++ks) {
      const int sl = ((ks * 4 + quad) ^ (r & 7)) * 8;
      short8 af[2], bf[8];
      #pragma unroll
      for (int i = 0; i < 2; ++i)
        af[i] = *(const short8*)(As + (w * 32 + i * 16 + r) * 64 + sl);
      #pragma unroll
      for (int j = 0; j < 8; ++j)
        bf[j] = *(const short8*)(Bs + (j * 16 + r) * 64 + sl);
      #pragma unroll
      for (int i = 0; i < 2; ++i)
        #pragma unroll
        for (int j = 0; j < 8; ++j)
          acc[i][j] = __builtin_amdgcn_mfma_f32_16x16x32_bf16(af[i], bf[j], acc[i][j], 0, 0, 0);
    }
  }
  // C/D layout: col=lane&15, row=quad*4+reg (m89-verified).
  // Diagonal (fp32, pre-rounding) -- Ht diag == H diag.
  if (blockIdx.x == blockIdx.y) {
    #pragma unroll
    for (int i = 0; i < 2; ++i) {
      const int rowg = m0 + w * 32 + i * 16 + quad * 4;
      #pragma unroll
      for (int j = 0; j < 8; ++j) {
        const int colg = n0 + j * 16 + r;
        #pragma unroll
        for (int g = 0; g < 4; ++g)
          if (rowg + g == colg) diag[c * N2 + colg] = acc[i][j][g];
      }
    }
  }
  // Row-sum partials (rows of Ht = cols of H): j-sum in-reg, r-sum via shfl.
  #pragma unroll
  for (int i = 0; i < 2; ++i)
    #pragma unroll
    for (int g = 0; g < 4; ++g) {
      float rs = 0.f;
      #pragma unroll
      for (int j = 0; j < 8; ++j) rs += acc[i][j][g];
      rs += __shfl_xor(rs, 1);
      rs += __shfl_xor(rs, 2);
      rs += __shfl_xor(rs, 4);
      rs += __shfl_xor(rs, 8);
      if (r == 0)
        csp[((size_t)(c * 16) + blockIdx.x) * N2 + m0 + w * 32 + i * 16 + quad * 4 + g] = rs;
    }
  // Two-phase coalescing store of C' (row-major, NOT transposed):
  // phase h covers rows h*64..h*64+63 (w-pairs); tb [64][136] u16.
  // Each thread copies one FULL 32-u16 segment (4x uint4): 64 rows x 4 segs
  // x 32 u16 = 8192 = whole 128-col x 64-row half-tile. (R9 bug: only
  // 2x uint4 copied -> half of Ht unwritten.)
  {
    u16* tb = SM;
    u16* Cc = Cout + (size_t)c * NN;
    #pragma unroll
    for (int h = 0; h < 2; ++h) {
      __syncthreads();             // h=0: MFMA LDS reads done; h=1: prev copy done
      if ((w >> 1) == h) {
        #pragma unroll
        for (int i = 0; i < 2; ++i)
          #pragma unroll
          for (int j = 0; j < 8; ++j)
            #pragma unroll
            for (int g = 0; g < 4; ++g)
              tb[((w & 1) * 32 + i * 16 + quad * 4 + g) * 136 + j * 16 + r] = f2b(acc[i][j][g]);
      }
      __syncthreads();
      const int row = t >> 2, seg = t & 3;
      const u16* ps = tb + row * 136 + seg * 32;
      uint4* pd = (uint4*)(Cc + (size_t)(m0 + h * 64 + row) * N2 + n0 + seg * 32);
      pd[0] = ((const uint4*)ps)[0];
      pd[1] = ((const uint4*)ps)[1];
      pd[2] = ((const uint4*)ps)[2];
      pd[3] = ((const uint4*)ps)[3];
    }
  }
}

// ---------------------------------------------------------------------------
// zgemm (+dcol fused, tail-free): per block (mt, split, c), K-split 16:
//   1) MFMA: Zp[split][c][k][i] partial over j in split's 128-range
//      (disjoint partial buffers -- no atomics, no waits).
//   2) recompute ci/wv slice for its 128 i-rows from csp/diag1 (L2-hot).
//      split==0 blocks also publish the ci slice for yfix (disjoint).
//   3) dcol elementwise over its 128x128 (i x j) region: Ht (L2-hot from
//      staging) + a1r (HBM) -> disjoint dp/cp slices [c][mt][split*128..].
// ---------------------------------------------------------------------------
__global__ __launch_bounds__(256, 2) void zgemm_kernel(
    const u16* __restrict__ Ht, const u16* __restrict__ Xwt,
    const u16* __restrict__ a1r, const float* __restrict__ csp,
    const float* __restrict__ diag1, float* __restrict__ Zp,
    float* __restrict__ ci, float* __restrict__ dp, float* __restrict__ cp)
{
  const int c = blockIdx.z, split = blockIdx.y, mt = blockIdx.x;
  const int m0 = mt * 128;
  const u16* Ac = Ht + (size_t)c * NN;
  const int t = threadIdx.x, w = t >> 6, lane = t & 63;
  const int quad = lane >> 4, r = lane & 15;
  __shared__ u16 SMZ[128 * 64 + 64 * 64];   // As | Bs (24 KB)
  u16* As = SMZ;
  u16* Bs = SMZ + 128 * 64;

  v4f zero4 = { 0.f, 0.f, 0.f, 0.f };
  v4f acc[2][4];
  #pragma unroll
  for (int i = 0; i < 2; ++i)
    #pragma unroll
    for (int j = 0; j < 4; ++j) acc[i][j] = zero4;

  const int srow = lane >> 3;
  const int sgran = (lane & 7) ^ srow;

  #pragma unroll
  for (int kk = 0; kk < 2; ++kk) {
    const int kt = split * 128 + kk * 64;
    __syncthreads();
    #pragma unroll
    for (int i = 0; i < 4; ++i) {
      const int chunk = i * 4 + w;
      const u16* ga = Ac + (size_t)(m0 + chunk * 8 + srow) * N2 + kt + sgran * 8;
      __builtin_amdgcn_global_load_lds((guint*)ga, (luint*)(As + chunk * 512), 16, 0, 0);
    }
    #pragma unroll
    for (int i = 0; i < 2; ++i) {
      const int chunk = i * 4 + w;
      const u16* gb = Xwt + (size_t)(chunk * 8 + srow) * N2 + kt + sgran * 8;
      __builtin_amdgcn_global_load_lds((guint*)gb, (luint*)(Bs + chunk * 512), 16, 0, 0);
    }
    __syncthreads();
    #pragma unroll
    for (int ks = 0; ks < 2; ++ks) {
      const int sl = ((ks * 4 + quad) ^ (r & 7)) * 8;
      short8 af[2], bf[4];
      #pragma unroll
      for (int i = 0; i < 2; ++i)
        af[i] = *(const short8*)(As + (w * 32 + i * 16 + r) * 64 + sl);
      #pragma unroll
      for (int j = 0; j < 4; ++j)
        bf[j] = *(const short8*)(Bs + (j * 16 + r) * 64 + sl);
      #pragma unroll
      for (int i = 0; i < 2; ++i)
        #pragma unroll
        for (int j = 0; j < 4; ++j)
          acc[i][j] = __builtin_amdgcn_mfma_f32_16x16x32_bf16(af[i], bf[j], acc[i][j], 0, 0, 0);
    }
  }
  const size_t pbase = (size_t)(split * 2 + c) * 64;
  #pragma unroll
  for (int i = 0; i < 2; ++i) {
    const int rowg = m0 + w * 32 + i * 16 + quad * 4;
    #pragma unroll
    for (int j = 0; j < 4; ++j) {
      const int colg = j * 16 + r;
      *(v4f*)(Zp + (pbase + colg) * (size_t)N2 + rowg) = acc[i][j];
    }
  }
  // --- ci/wv slice for this block's 128 rows (LDS floats [0..256)) ---
  __syncthreads();                       // MFMA LDS reads done; reuse SMZ
  float* ci_l = (float*)SMZ;             // [128]
  float* wv_l = ci_l + 128;              // [128]
  if (t < 128) {
    const int i = m0 + t;
    float cs = 0.f;
    #pragma unroll
    for (int s = 0; s < 16; ++s) cs += csp[((size_t)(c * 16) + s) * N2 + i];
    const float deg = cs - diag1[c * N2 + i];
    const float v = (deg == 0.f) ? 0.f : 1.f / (deg + 1e-8f);
    ci_l[t] = v;
    wv_l[t] = v * deg;
    if (split == 0) ci[c * N2 + i] = v;  // publish for yfix (disjoint slices)
  }
  __syncthreads();
  // --- dcol elementwise: thread = 4 cols (j4) x 8-row group (ig) per kk ---
  const int j4 = (t & 15) * 4, ig = t >> 4;
  float dacc[2][4], cacc[2][4];
  #pragma unroll
  for (int kk = 0; kk < 2; ++kk) {
    const int gj = split * 128 + kk * 64 + j4;
    #pragma unroll
    for (int u = 0; u < 4; ++u) { dacc[kk][u] = 0.f; cacc[kk][u] = 0.f; }
    for (int ii = 0; ii < 8; ++ii) {
      const int i = m0 + ig * 8 + ii;
      uint2 hu = *(const uint2*)(Ht  + (size_t)c * NN + (size_t)i * N2 + gj);
      uint2 au = *(const uint2*)(a1r + (size_t)c * NN + (size_t)i * N2 + gj);
      float h[4], a[4];
      h[0] = b2f_bits(hu.x << 16); h[1] = b2f_bits(hu.x & 0xffff0000u);
      h[2] = b2f_bits(hu.y << 16); h[3] = b2f_bits(hu.y & 0xffff0000u);
      a[0] = b2f_bits(au.x << 16); a[1] = b2f_bits(au.x & 0xffff0000u);
      a[2] = b2f_bits(au.y << 16); a[3] = b2f_bits(au.y & 0xffff0000u);
      const float cq = ci_l[ig * 8 + ii];
      const float wq = wv_l[ig * 8 + ii];
      #pragma unroll
      for (int u = 0; u < 4; ++u) {
        cacc[kk][u] += wq * a[u];
        const float tv = cq * h[u] * a[u];
        dacc[kk][u] += (i == gj + u) ? 0.f : tv;
      }
    }
  }
  // reduce over 16 ig-groups via LDS; dacc in cols [0,128), cacc in [128,256)
  float* red = ci_l + 256;               // [16][256] floats = 16 KB
  __syncthreads();
  #pragma unroll
  for (int kk = 0; kk < 2; ++kk)
    #pragma unroll
    for (int u = 0; u < 4; ++u) {
      red[ig * 256 + kk * 64 + j4 + u] = dacc[kk][u];
      red[ig * 256 + 128 + kk * 64 + j4 + u] = cacc[kk][u];
    }
  __syncthreads();
  {
    float v = 0.f;
    #pragma unroll
    for (int g = 0; g < 16; ++g) v += red[g * 256 + t];
    if (t < 128)
      dp[((size_t)(c * 16) + mt) * N2 + split * 128 + t] = v;
    else
      cp[((size_t)(c * 16) + mt) * N2 + split * 128 + (t - 128)] = v;
  }
}

// yfix: Y^T[c][k][i] = bf16( ci[i] * (Z[i][k] - diag1[i]*Xw[i][k]) ),
// Z reduced from 16 split partials. Blocks 0..15 additionally run fin
// (reduce dp/cp over 16 mt partials -> diag2/dinv2; inputs complete).
// ---------------------------------------------------------------------------
__global__ __launch_bounds__(256) void yfix_kernel(
    const float* __restrict__ Zp, const float* __restrict__ ci,
    const float* __restrict__ diag1, const u16* __restrict__ Xwt,
    u16* __restrict__ Yt, const float* __restrict__ dp,
    const float* __restrict__ cp, float* __restrict__ diag2,
    float* __restrict__ dinv2)
{
  const int idx = blockIdx.x * 256 + threadIdx.x;  // [0, 262144)
  const int i = idx & 2047, k = (idx >> 11) & 63, c = idx >> 17;
  float z = 0.f;
  #pragma unroll
  for (int s = 0; s < 16; ++s)
    z += Zp[(size_t)((s * 2 + c) * 64 + k) * N2 + i];
  const float xw = b2f(Xwt[(size_t)k * N2 + i]);
  const float y = ci[c * N2 + i] * (z - diag1[c * N2 + i] * xw);
  Yt[(size_t)c * 64 * N2 + (size_t)k * N2 + i] = f2b(y);
  // fused fin (16 of 1024 blocks)
  if (blockIdx.x < 16) {
    const int idx2 = blockIdx.x * 256 + threadIdx.x;  // [0, 4096)
    const int c2 = idx2 >> 11, i2 = idx2 & 2047;
    float ds = 0.f, cs = 0.f;
    #pragma unroll
    for (int b = 0; b < 16; ++b) {
      ds += dp[(size_t)(c2 * 16 + b) * N2 + i2];
      cs += cp[(size_t)(c2 * 16 + b) * N2 + i2];
    }
    const float deg = cs - ds + 1.0f;   // add=True: diag set to 1 -> +1
    diag2[idx2] = ds;
    dinv2[idx2] = (deg == 0.f) ? 0.f : 1.f / (deg + 1e-8f);
  }
}

// ---------------------------------------------------------------------------
// tgemm: Tp[split][c][i][k] partial of sum_j a1t[i][j]*Yt[c][k][j] over j in
// split's 128-range. K-split 16 -> 1024 blocks, 2+/CU.
// ---------------------------------------------------------------------------
__global__ __launch_bounds__(256, 2) void tgemm_kernel(
    const u16* __restrict__ a1t, const u16* __restrict__ Yt, float* __restrict__ Tp)
{
  const int c = blockIdx.z, split = blockIdx.y;
  const int m0 = blockIdx.x * 128;
  const u16* Ac = a1t + (size_t)c * NN;
  const u16* Bc = Yt + (size_t)c * (64 * (size_t)N2);
  const int t = threadIdx.x, w = t >> 6, lane = t & 63;
  const int quad = lane >> 4, r = lane & 15;
  __shared__ u16 As[128 * 64];
  __shared__ u16 Bs[64 * 64];

  v4f zero4 = { 0.f, 0.f, 0.f, 0.f };
  v4f acc[2][4];
  #pragma unroll
  for (int i = 0; i < 2; ++i)
    #pragma unroll
    for (int j = 0; j < 4; ++j) acc[i][j] = zero4;

  const int srow = lane >> 3;
  const int sgran = (lane & 7) ^ srow;

  #pragma unroll
  for (int kk = 0; kk < 2; ++kk) {
    const int kt = split * 128 + kk * 64;
    __syncthreads();
    #pragma unroll
    for (int i = 0; i < 4; ++i) {
      const int chunk = i * 4 + w;
      const u16* ga = Ac + (size_t)(m0 + chunk * 8 + srow) * N2 + kt + sgran * 8;
      __builtin_amdgcn_global_load_lds((guint*)ga, (luint*)(As + chunk * 512), 16, 0, 0);
    }
    #pragma unroll
    for (int i = 0; i < 2; ++i) {
      const int chunk = i * 4 + w;
      const u16* gb = Bc + (size_t)(chunk * 8 + srow) * N2 + kt + sgran * 8;
      __builtin_amdgcn_global_load_lds((guint*)gb, (luint*)(Bs + chunk * 512), 16, 0, 0);
    }
    __syncthreads();
    #pragma unroll
    for (int ks = 0; ks < 2; ++ks) {
      const int sl = ((ks * 4 + quad) ^ (r & 7)) * 8;
      short8 af[2], bf[4];
      #pragma unroll
      for (int i = 0; i < 2; ++i)
        af[i] = *(const short8*)(As + (w * 32 + i * 16 + r) * 64 + sl);
      #pragma unroll
      for (int j = 0; j < 4; ++j)
        bf[j] = *(const short8*)(Bs + (j * 16 + r) * 64 + sl);
      #pragma unroll
      for (int i = 0; i < 2; ++i)
        #pragma unroll
        for (int j = 0; j < 4; ++j)
          acc[i][j] = __builtin_amdgcn_mfma_f32_16x16x32_bf16(af[i], bf[j], acc[i][j], 0, 0, 0);
    }
  }
  const size_t pbase = (size_t)(split * 2 + c) * 2048;
  #pragma unroll
  for (int i = 0; i < 2; ++i) {
    const int rowg = m0 + w * 32 + i * 16 + quad * 4;
    #pragma unroll
    for (int j = 0; j < 4; ++j) {
      const int colg = j * 16 + r;
      #pragma unroll
      for (int g = 0; g < 4; ++g)
        Tp[(pbase + rowg + g) * 64 + colg] = acc[i][j][g];
    }
  }
}

// out[i][c*64+k] = relu( dinv2 * (T - diag2*xw + xw) ), fp32; T from 16 splits
__global__ void epilogue_kernel(const float* __restrict__ Tp, const float* __restrict__ diag2,
                                const float* __restrict__ dinv2, const u16* __restrict__ Xwt,
                                float* __restrict__ out)
{
  const int idx = blockIdx.x * 256 + threadIdx.x;
  const int k = idx & 63;
  const int c = (idx >> 6) & 1;
  const int i = idx >> 7;
  float T = 0.f;
  #pragma unroll
  for (int s = 0; s < 16; ++s)
    T += Tp[((size_t)(s * 2 + c) * 2048 + i) * 64 + k];
  const float hd = diag2[c * N2 + i];
  const float dv = dinv2[c * N2 + i];
  const float xw = b2f(Xwt[(size_t)k * N2 + i]);
  float v = dv * (T - hd * xw + xw);
  v = v > 0.f ? v : 0.f;
  out[(size_t)i * 128 + c * 64 + k] = v;
}

// ---------------------------------------------------------------------------
// Workspace layout (bytes), all reads preceded by writes, no cross-block sync:
//   abf   @ 0          (16.78 MB bf16)  -- dead after gemm1
//   bbt   @ 16777216   (16.78 MB bf16)  -- dead after gemm1
//   a1t   @ 33554432   (16.78 MB bf16)  -- dead after tgemm
//   a1r   @ 50331648   (16.78 MB bf16)  -- dead after zgemm
//   Ht    @ 67108864   (16.78 MB bf16)  -- dead after zgemm
//   Xwt   @ 83886080   (256 KB bf16 [64][2048])
//   cspa  @ 84148224   (256 KB fp32 [2][16][2048])
//   diag1 @ 84410368   (16 KB)
//   ci1   @ 84426752   (16 KB)
//   diag2 @ 84459520   (16 KB)
//   dinv2 @ 84475904   (16 KB)          -- end 84492288
//   Zp    @ 0          (16.78 MB fp32 [16][2][64][2048], over abf)
//   dp    @ 16777216   (256 KB fp32 [2][16][2048], over bbt)
//   cp    @ 17039360   (256 KB, over bbt)
//   Yt    @ 17301504   (512 KB bf16 [2][64][2048], over bbt)
//   Tp    @ 50331648   (16.78 MB fp32 [16][2][2048][64], over a1r)
// ---------------------------------------------------------------------------
extern "C" void kernel_launch(void* const* d_in, const int* in_sizes, int n_in,
                              void* d_out, int out_size, void* d_ws, size_t ws_size,
                              hipStream_t stream) {
  const float* A  = (const float*)d_in[0];
  const float* X  = (const float*)d_in[1];
  const float* w1 = (const float*)d_in[2];
  const float* w2 = (const float*)d_in[3];
  const float* w3 = (const float*)d_in[4];
  const float* W  = (const float*)d_in[5];
  float* out = (float*)d_out;
  char* ws = (char*)d_ws;

  u16*   abf   = (u16*)(ws + 0);
  u16*   bbt   = (u16*)(ws + 16777216);
  u16*   a1t   = (u16*)(ws + 33554432);
  u16*   a1r   = (u16*)(ws + 50331648);
  u16*   Ht    = (u16*)(ws + 67108864);
  u16*   Xwt   = (u16*)(ws + 83886080);
  float* cspa  = (float*)(ws + 84148224);
  float* diag1 = (float*)(ws + 84410368);
  float* ci1   = (float*)(ws + 84426752);
  float* diag2 = (float*)(ws + 84459520);
  float* dinv2 = (float*)(ws + 84475904);
  float* Zp    = (float*)(ws + 0);
  float* dp    = (float*)(ws + 16777216);
  float* cp    = (float*)(ws + 17039360);
  u16*   Yt    = (u16*)(ws + 17301504);
  float* Tp    = (float*)(ws + 50331648);

  conv_kernel<<<dim3(32, 32), 512, 0, stream>>>(A, w1, w2, w3, X, W, abf, bbt, a1t, a1r, Xwt);
  // A = bbt, Bt = abf  ->  C' = Ht directly (see kernel comment).
  gemm_kernel<<<dim3(16, 16, 2), 256, 0, stream>>>(bbt, abf, Ht, cspa, diag1);
  zgemm_kernel<<<dim3(16, 16, 2), 256, 0, stream>>>(Ht, Xwt, a1r, cspa, diag1, Zp, ci1, dp, cp);
  yfix_kernel<<<1024, 256, 0, stream>>>(Zp, ci1, diag1, Xwt, Yt, dp, cp, diag2, dinv2);
  tgemm_kernel<<<dim3(16, 16, 2), 256, 0, stream>>>(a1t, Yt, Tp);
  epilogue_kernel<<<1024, 256, 0, stream>>>(Tp, diag2, dinv2, Xwt, out);
}